// Round 1
// baseline (288.661 us; speedup 1.0000x reference)
//
#include <hip/hip_runtime.h>

constexpr int Bv  = 8;
constexpr int NQ  = 512;
constexpr int NKV = 512;
constexpr int Hh  = 16;
constexpr int Dd  = 256;

// C[m][n] = sum_k A[m][k] * W[n][k] + bias[n];  M=4096, N=256, K=256
// 64x64 tile, 256 threads, 4x4 per thread, K-major LDS tiles (stride 68:
// 16B-aligned float4 rows, <=2-way banks = free).
__global__ __launch_bounds__(256) void gemm_abt(
    const float* __restrict__ A, const float* __restrict__ W,
    const float* __restrict__ bias, float* __restrict__ C) {
  __shared__ float As[16][68];
  __shared__ float Ws[16][68];
  const int t  = threadIdx.x;
  const int tx = t & 15;        // n-group
  const int ty = t >> 4;        // m-group
  const int m0 = blockIdx.x * 64;
  const int n0 = blockIdx.y * 64;
  const int lr = t >> 2;        // 0..63 row for staging
  const int lk = (t & 3) << 2;  // 0,4,8,12 k offset

  float acc[4][4] = {};

  for (int k0 = 0; k0 < 256; k0 += 16) {
    __syncthreads();
    const float4 av = *(const float4*)(A + (size_t)(m0 + lr) * 256 + k0 + lk);
    const float4 wv = *(const float4*)(W + (size_t)(n0 + lr) * 256 + k0 + lk);
    As[lk + 0][lr] = av.x; As[lk + 1][lr] = av.y;
    As[lk + 2][lr] = av.z; As[lk + 3][lr] = av.w;
    Ws[lk + 0][lr] = wv.x; Ws[lk + 1][lr] = wv.y;
    Ws[lk + 2][lr] = wv.z; Ws[lk + 3][lr] = wv.w;
    __syncthreads();
#pragma unroll
    for (int k = 0; k < 16; ++k) {
      float a_[4], w_[4];
      *(float4*)a_ = *(const float4*)&As[k][ty << 2];
      *(float4*)w_ = *(const float4*)&Ws[k][tx << 2];
#pragma unroll
      for (int i = 0; i < 4; ++i)
#pragma unroll
        for (int j = 0; j < 4; ++j)
          acc[i][j] = fmaf(a_[i], w_[j], acc[i][j]);
    }
  }

  const float4 bvv = *(const float4*)(bias + n0 + (tx << 2));
  const float bb[4] = {bvv.x, bvv.y, bvv.z, bvv.w};
#pragma unroll
  for (int i = 0; i < 4; ++i) {
    float4 cv;
    cv.x = acc[i][0] + bb[0];
    cv.y = acc[i][1] + bb[1];
    cv.z = acc[i][2] + bb[2];
    cv.w = acc[i][3] + bb[3];
    *(float4*)(C + (size_t)(m0 + (ty << 2) + i) * 256 + n0 + (tx << 2)) = cv;
  }
}

// Fused masked softmax + per-head aggregation + L2-norm rescale.
// Grid: 512 blocks = (b, 8-q chunk). Block 256 threads.
// Thread layout: h = t&15, d4 = (t>>4)&3 (4 dh columns), q2 = t>>6 (2 q rows).
// Single pass, no max-subtraction (messages ~ N(0,1); masked -> e = 0).
// attn_out[q, h*16+d] = o * sqrt(ssq) / sum^2   where e = mask*exp(msg),
// o = sum_k e * proj,  sum = sum_k e,  ssq = sum_k e^2.
__global__ __launch_bounds__(256) void attn_kernel(
    const float* __restrict__ msg, const int* __restrict__ adj,
    const float* __restrict__ proj, float* __restrict__ attn_out) {
  __shared__ float Psh[32 * Dd];  // 32 KB: proj[b, k0:k0+32, :]

  const int t  = threadIdx.x;
  const int h  = t & 15;
  const int d4 = (t >> 4) & 3;
  const int q2 = t >> 6;  // 0..3
  const int b  = blockIdx.x >> 6;
  const int q0 = (blockIdx.x & 63) * 8 + q2 * 2;  // rows q0, q0+1
  const int dcol = h * 16 + d4 * 4;

  const float* m0p = msg + ((size_t)(b * NQ + q0) * NKV) * Hh + h;
  const float* m1p = m0p + (size_t)NKV * Hh;
  const int*   a0p = adj + (size_t)(b * NQ + q0) * NKV;
  const int*   a1p = a0p + NKV;
  const float* pb  = proj + (size_t)b * NKV * Dd;

  float o0[4] = {}, o1[4] = {};
  float s0 = 0.f, s1 = 0.f, r0 = 0.f, r1 = 0.f;

  for (int k0 = 0; k0 < NKV; k0 += 32) {
    __syncthreads();
    {  // stage proj[b, k0:k0+32, :] -> LDS (fully coalesced float4 copy)
      const float4* src = (const float4*)(pb + (size_t)k0 * Dd);
      float4* dst = (float4*)Psh;
#pragma unroll
      for (int i = 0; i < 8; ++i) dst[t + i * 256] = src[t + i * 256];
    }
    __syncthreads();

#pragma unroll 2
    for (int kk4 = 0; kk4 < 32; kk4 += 4) {
      int av0[4], av1[4];
      *(int4*)av0 = *(const int4*)(a0p + k0 + kk4);
      *(int4*)av1 = *(const int4*)(a1p + k0 + kk4);
      float mv0[4], mv1[4];
#pragma unroll
      for (int j = 0; j < 4; ++j) {
        mv0[j] = m0p[(size_t)(k0 + kk4 + j) * Hh];
        mv1[j] = m1p[(size_t)(k0 + kk4 + j) * Hh];
      }
#pragma unroll
      for (int j = 0; j < 4; ++j) {
        const int kk = kk4 + j;
        const float e0 = (av0[j] > 0) ? __expf(mv0[j]) : 0.0f;
        const float e1 = (av1[j] > 0) ? __expf(mv1[j]) : 0.0f;
        s0 += e0; r0 = fmaf(e0, e0, r0);
        s1 += e1; r1 = fmaf(e1, e1, r1);
        float p[4];
        *(float4*)p = *(const float4*)(Psh + kk * Dd + dcol);
#pragma unroll
        for (int d = 0; d < 4; ++d) {
          o0[d] = fmaf(e0, p[d], o0[d]);
          o1[d] = fmaf(e1, p[d], o1[d]);
        }
      }
    }
  }

  const float w0 = sqrtf(r0) / (s0 * s0);
  const float w1 = sqrtf(r1) / (s1 * s1);
  float4 out0, out1;
  out0.x = o0[0] * w0; out0.y = o0[1] * w0;
  out0.z = o0[2] * w0; out0.w = o0[3] * w0;
  out1.x = o1[0] * w1; out1.y = o1[1] * w1;
  out1.z = o1[2] * w1; out1.w = o1[3] * w1;
  *(float4*)(attn_out + (size_t)(b * NQ + q0) * Dd + dcol)     = out0;
  *(float4*)(attn_out + (size_t)(b * NQ + q0 + 1) * Dd + dcol) = out1;
}

extern "C" void kernel_launch(void* const* d_in, const int* in_sizes, int n_in,
                              void* d_out, int out_size, void* d_ws, size_t ws_size,
                              hipStream_t stream) {
  const float* v_inv    = (const float*)d_in[0];
  const float* messages = (const float*)d_in[1];
  const int*   adj      = (const int*)d_in[2];
  const float* W_in     = (const float*)d_in[3];
  const float* b_in     = (const float*)d_in[4];
  const float* W_out    = (const float*)d_in[5];
  const float* b_out    = (const float*)d_in[6];
  float* out = (float*)d_out;

  float* proj = (float*)d_ws;                       // 4 MB: [B, NKV, D]
  float* attn = proj + (size_t)Bv * NKV * Dd;       // 4 MB: [B, NQ, D]

  dim3 gemm_grid(4096 / 64, 256 / 64);
  gemm_abt<<<gemm_grid, 256, 0, stream>>>(v_inv, W_in, b_in, proj);
  attn_kernel<<<512, 256, 0, stream>>>(messages, adj, proj, attn);
  gemm_abt<<<gemm_grid, 256, 0, stream>>>(attn, W_out, b_out, out);
}